// Round 17
// baseline (606.442 us; speedup 1.0000x reference)
//
#include <hip/hip_runtime.h>
#include <hip/hip_bf16.h>

typedef unsigned short u16;
typedef unsigned long long u64;
typedef __attribute__((ext_vector_type(8))) short bf16x8;
typedef __attribute__((ext_vector_type(4))) float f32x4;

static __device__ __forceinline__ u16 f2bf(float f) {
    union { float f; unsigned u; } cv; cv.f = f;
    unsigned u = cv.u;
    unsigned r = u + 0x7FFF + ((u >> 16) & 1);   // round-to-nearest-even
    return (u16)(r >> 16);
}
static __device__ __forceinline__ float bf2f(u16 b) {
    union { unsigned u; float f; } cv; cv.u = ((unsigned)b) << 16;
    return cv.f;
}
static __device__ __forceinline__ float sigmoidf_(float x) {
    return 1.0f / (1.0f + __expf(-x));
}
static __device__ __forceinline__ float tanhf_(float x) {
    float e = __expf(-2.f * fabsf(x));
    float t = (1.f - e) / (1.f + e);
    return copysignf(t, x);
}

// ---------------------------------------------------------------------------
// One-launch preprocessing. Job map (714 blocks):
//   0..95    wihT tiles       96..287  whhT tiles     288..319 mlpT tiles
//   320..327 w2T tiles        328      bfv            329..456 h0 zero
//   457      flags zero       458..713 WfT direct (wv@wo)^T
__global__ __launch_bounds__(256) void prep_all(
    const float* __restrict__ wv, const float* __restrict__ wo,
    const float* __restrict__ wih, const float* __restrict__ whh,
    const float* __restrict__ mlp, const float* __restrict__ w2,
    const float* __restrict__ bv, const float* __restrict__ bo,
    u16* __restrict__ WfT, u16* __restrict__ wihT,
    u16* __restrict__ whhT, u16* __restrict__ mlpT, u16* __restrict__ w2T,
    float* __restrict__ bfv, u16* __restrict__ h0_bf,
    unsigned* __restrict__ flags)
{
    __shared__ u16 t[64][66];
    int bid = blockIdx.x, tid = threadIdx.x;

    if (bid >= 458) {                     // WfT[j][i] = bf16(sum_k wv[i][k]*wo[k][j])
        int j = bid - 458, i = tid;
        float s = 0.f;
        for (int k = 0; k < 256; ++k) s = fmaf(wv[i * 256 + k], wo[k * 256 + j], s);
        WfT[j * 256 + i] = f2bf(s);
        return;
    }
    if (bid == 328) {                     // bfv = bo + bv@wo
        int j = tid;
        float s = bo[j];
        for (int k = 0; k < 256; ++k) s = fmaf(bv[k], wo[k * 256 + j], s);
        bfv[j] = s;
        return;
    }
    if (bid >= 329 && bid < 457) {        // zero h0_bf (512KB)
        int i = ((bid - 329) * 256 + tid) * 2;
        u64* p = (u64*)h0_bf;
        p[i] = 0; p[i + 1] = 0;
        return;
    }
    if (bid == 457) {                     // zero flags
        unsigned* p = flags;
        for (int i = tid; i < 32 * 8 * 32; i += 256) p[i] = 0u;
        return;
    }

    // tiled transpose-convert jobs: dst[n*K+k] = bf16(src[k*N+n])
    const float* src; u16* dst; int K, N, bx, by;
    if (bid < 96)       { src = wih; dst = wihT; K = 256; N = 1536; int l = bid;       bx = l & 3; by = l >> 2; }
    else if (bid < 288) { src = whh; dst = whhT; K = 512; N = 1536; int l = bid - 96;  bx = l & 7; by = l >> 3; }
    else if (bid < 320) { src = mlp; dst = mlpT; K = 512; N = 256;  int l = bid - 288; bx = l & 7; by = l >> 3; }
    else                { src = w2;  dst = w2T;  K = 128; N = 256;  int l = bid - 320; bx = l & 1; by = l >> 1; }

    int k0 = bx * 64, n0 = by * 64;
    int r = tid >> 4, c4 = (tid & 15) * 4;
#pragma unroll
    for (int p = 0; p < 4; ++p) {
        int row = r + p * 16;
        float4 v = *(const float4*)&src[(size_t)(k0 + row) * N + n0 + c4];
        t[c4 + 0][row] = f2bf(v.x);
        t[c4 + 1][row] = f2bf(v.y);
        t[c4 + 2][row] = f2bf(v.z);
        t[c4 + 3][row] = f2bf(v.w);
    }
    __syncthreads();
    int rr = tid >> 3, cc = (tid & 7) * 8;
#pragma unroll
    for (int p = 0; p < 2; ++p) {
        int row = rr + p * 32;
        u16 pack[8];
#pragma unroll
        for (int j = 0; j < 8; ++j) pack[j] = t[row][cc + j];
        *(uint4*)&dst[(size_t)(n0 + row) * K + k0 + cc] = *(uint4*)pack;
    }
}

// ---------------------------------------------------------------------------
// Fused action-encoder + LayerNorm, MFMA version. 64 positions per block.
__global__ __launch_bounds__(256) void ae_ln_mfma(
    const float* __restrict__ action,
    const float* __restrict__ w1, const float* __restrict__ b1,
    const u16* __restrict__ w2T, const float* __restrict__ b2,
    const float* __restrict__ g, const float* __restrict__ be,
    u16* __restrict__ kvbf)
{
    __shared__ u16 lB[256][136];
    __shared__ u16 lA[64][136];
    int tid = threadIdx.x;
    long base = (long)blockIdx.x * 64;

    for (int idx = tid; idx < 256 * 16; idx += 256) {
        int r = idx >> 4, ch = (idx & 15) * 8;
        *(uint4*)&lB[r][ch] = *(const uint4*)&w2T[r * 128 + ch];
    }
    for (int idx = tid; idx < 8192; idx += 256) {
        int r = idx >> 7, k = idx & 127;
        float a0 = action[(base + r) * 2], a1 = action[(base + r) * 2 + 1];
        float v = fmaf(a1, w1[128 + k], fmaf(a0, w1[k], b1[k]));
        lA[r][k] = f2bf(v > 0.f ? v : 0.f);
    }
    __syncthreads();

    int wv = tid >> 6, l = tid & 63;
    int fr = l & 15, fq = l >> 4;
    f32x4 acc[4][4] = {};
#pragma unroll
    for (int ks = 0; ks < 4; ++ks) {
        bf16x8 a[4], b[4];
#pragma unroll
        for (int mi = 0; mi < 4; ++mi) a[mi] = *(bf16x8*)&lA[mi * 16 + fr][ks * 32 + fq * 8];
#pragma unroll
        for (int ni = 0; ni < 4; ++ni) b[ni] = *(bf16x8*)&lB[wv * 64 + ni * 16 + fr][ks * 32 + fq * 8];
#pragma unroll
        for (int mi = 0; mi < 4; ++mi)
#pragma unroll
            for (int ni = 0; ni < 4; ++ni)
                acc[mi][ni] = __builtin_amdgcn_mfma_f32_16x16x32_bf16(a[mi], b[ni], acc[mi][ni], 0, 0, 0);
    }
    __syncthreads();

    float* e = (float*)&lB[0][0];
#pragma unroll
    for (int mi = 0; mi < 4; ++mi)
#pragma unroll
        for (int ni = 0; ni < 4; ++ni) {
            int col = wv * 64 + ni * 16 + fr;
            float bb = b2[col];
#pragma unroll
            for (int reg = 0; reg < 4; ++reg)
                e[(mi * 16 + fq * 4 + reg) * 261 + col] = acc[mi][ni][reg] + bb;
        }
    __syncthreads();

    int t = tid >> 2, sub = tid & 3;
    float s = 0.f, ss = 0.f;
#pragma unroll
    for (int i = 0; i < 64; ++i) {
        float v = e[t * 261 + sub + i * 4];
        s += v; ss += v * v;
    }
    s += __shfl_xor(s, 1); ss += __shfl_xor(ss, 1);
    s += __shfl_xor(s, 2); ss += __shfl_xor(ss, 2);
    float m = s * (1.f / 256.f);
    float var = ss * (1.f / 256.f) - m * m;
    float rs = rsqrtf(var + 1e-5f);
#pragma unroll
    for (int i8 = 0; i8 < 8; ++i8) {
        u16 pack[8];
#pragma unroll
        for (int j = 0; j < 8; ++j) {
            int col = sub * 64 + i8 * 8 + j;
            float v = (e[t * 261 + col] - m) * rs * g[col] + be[col];
            pack[j] = f2bf(v);
        }
        *(uint4*)&kvbf[(base + t) * 256 + sub * 64 + i8 * 8] = *(uint4*)pack;
    }
}

// ---------------------------------------------------------------------------
// 128x128-tile bf16 GEMM, BK=64: C = A[M,K] @ BT[N,K]^T (+bias[col]) (+modes)
template <int MODE>
__global__ __launch_bounds__(256) void gemm128(
    const u16* __restrict__ A, const u16* __restrict__ BT,
    const float* __restrict__ bias, const float* __restrict__ resid,
    u16* __restrict__ outBf, float* __restrict__ outF,
    int N, int K)
{
    __shared__ u16 lA[128][72];
    __shared__ u16 lB[128][72];
    int tid = threadIdx.x;
    int bm = blockIdx.x * 128, bn = blockIdx.y * 128;

    f32x4 acc[4][4] = {};
    int w = tid >> 6, l = tid & 63;
    int wr = (w >> 1) * 64, wc = (w & 1) * 64;
    int fr = l & 15, fk = (l >> 4) * 8;

    for (int k0 = 0; k0 < K; k0 += 64) {
#pragma unroll
        for (int i = 0; i < 4; ++i) {
            int idx = tid + i * 256;
            int r = idx >> 3, c8 = (idx & 7) * 8;
            *(uint4*)&lA[r][c8] = *(const uint4*)&A[(long)(bm + r) * K + k0 + c8];
            *(uint4*)&lB[r][c8] = *(const uint4*)&BT[(long)(bn + r) * K + k0 + c8];
        }
        __syncthreads();
#pragma unroll
        for (int half = 0; half < 2; ++half) {
            int fo = half * 32 + fk;
            bf16x8 a[4], b[4];
#pragma unroll
            for (int mi = 0; mi < 4; ++mi) a[mi] = *(bf16x8*)&lA[wr + mi * 16 + fr][fo];
#pragma unroll
            for (int ni = 0; ni < 4; ++ni) b[ni] = *(bf16x8*)&lB[wc + ni * 16 + fr][fo];
#pragma unroll
            for (int mi = 0; mi < 4; ++mi)
#pragma unroll
                for (int ni = 0; ni < 4; ++ni)
                    acc[mi][ni] = __builtin_amdgcn_mfma_f32_16x16x32_bf16(a[mi], b[ni], acc[mi][ni], 0, 0, 0);
        }
        __syncthreads();
    }

#pragma unroll
    for (int mi = 0; mi < 4; ++mi)
#pragma unroll
        for (int ni = 0; ni < 4; ++ni) {
            int c = bn + wc + ni * 16 + fr;
            float bz = bias[c];
#pragma unroll
            for (int reg = 0; reg < 4; ++reg) {
                int r = bm + wr + mi * 16 + (l >> 4) * 4 + reg;
                float v = acc[mi][ni][reg] + bz;
                if constexpr (MODE == 0) {
                    v += resid[(long)r * N + c];
                    outBf[(long)r * N + c] = f2bf(v);
                } else if constexpr (MODE == 1) {
                    outBf[(long)r * N + c] = f2bf(v);
                } else {
                    outF[(long)r * N + c] = v;
                    if ((r & 511) == 511) outF[8388608 + (long)(r >> 9) * N + c] = v;
                }
            }
        }
}

// ---------------------------------------------------------------------------
// Persistent GRU v11 = v6 + gi computed IN THE POLL WINDOW (the one idle
// phase). Per step, after the flag store, all 12 waves compute gi(step+1)
// for this block's 16t x 192 gate-cols (8 MFMA/wave; x from L3, wih from
// L2-hot 96KB slice) into the gis LDS plane -- consumed by the NEXT step's
// epilogue (write/read separated by 3 barriers). Deletes the separate gi
// GEMM dispatch and its 96MB HBM write + re-read.
__global__ __launch_bounds__(768, 1) void gru_persistent11(
    const u16* __restrict__ whhT, const u16* __restrict__ wihT,
    const float* __restrict__ bhh, const float* __restrict__ bih,
    const u16* __restrict__ x_bf, const u16* __restrict__ h0_bf,
    u16* __restrict__ out_bf, unsigned* __restrict__ flags)
{
    __shared__ u64 lh64[2048];                       // swizzled h [16][512] bf16
    __shared__ __align__(16) float ghs[3][16][68];   // gh exchange
    __shared__ __align__(16) float gis[3][16][68];   // gi exchange (1-step ahead)
    u16* lh = (u16*)lh64;

    int tid = threadIdx.x;
    int bid = blockIdx.x;
    int tg = bid >> 3, cb = bid & 7;
    int tbase = tg * 16, cbase = cb * 64;

    int w = tid >> 6, l = tid & 63;
    int fr = l & 15, fo = l >> 4;
    int cpos = w & 3, gate = w >> 2;

    bf16x8 a[16];
    {
        const u16* wp = whhT + ((size_t)(gate << 9) + cbase + cpos * 16 + fr) * 512 + fo * 8;
#pragma unroll
        for (int kk = 0; kk < 16; ++kk)
            a[kk] = *(const bf16x8*)(wp + kk * 32);
    }
    const u16* wp2 = wihT + ((size_t)(gate << 9) + cbase + cpos * 16 + fr) * 256 + fo * 8;

    int et = tid >> 5, ec = (tid & 31) * 2;
    bool ep = tid < 512;
    float hreg0 = 0.f, hreg1 = 0.f;
    float bs_r0 = 0, bs_r1 = 0, bs_z0 = 0, bs_z1 = 0;
    float bi_n0 = 0, bi_n1 = 0, bh_n0 = 0, bh_n1 = 0;
    if (ep) {
        bs_r0 = bih[cbase + ec] + bhh[cbase + ec];
        bs_r1 = bih[cbase + ec + 1] + bhh[cbase + ec + 1];
        bs_z0 = bih[512 + cbase + ec] + bhh[512 + cbase + ec];
        bs_z1 = bih[512 + cbase + ec + 1] + bhh[512 + cbase + ec + 1];
        bi_n0 = bih[1024 + cbase + ec];  bi_n1 = bih[1024 + cbase + ec + 1];
        bh_n0 = bhh[1024 + cbase + ec];  bh_n1 = bhh[1024 + cbase + ec + 1];
    }

    // gi for step t -> gis plane (8 MFMA/wave, 4+4 sub-batched for reg pressure)
    auto gi_compute = [&](int t) {
        const u16* xp = x_bf + ((size_t)t * 512 + tbase + fr) * 256 + fo * 8;
        f32x4 gacc = {0.f, 0.f, 0.f, 0.f};
#pragma unroll
        for (int half = 0; half < 2; ++half) {
            bf16x8 xf[4], wf[4];
#pragma unroll
            for (int j = 0; j < 4; ++j) {
                int kk = half * 4 + j;
                xf[j] = *(const bf16x8*)(xp + kk * 32);
                wf[j] = *(const bf16x8*)(wp2 + kk * 32);
            }
#pragma unroll
            for (int j = 0; j < 4; ++j)
                gacc = __builtin_amdgcn_mfma_f32_16x16x32_bf16(wf[j], xf[j], gacc, 0, 0, 0);
        }
        *(f32x4*)&gis[gate][fr][cpos * 16 + fo * 4] = gacc;
    };

    gi_compute(0);   // prologue; visible by the time the first epilogue runs

    for (int step = 0; step < 64; ++step) {
        const u64* hb64 = (const u64*)(step ? out_bf + (size_t)(step - 1) * 262144
                                           : h0_bf);
#pragma unroll
        for (int i = 0; i < 3; ++i) {
            int idx = tid + i * 768;
            if (idx < 2048) {
                int r = idx >> 7, kw = idx & 127;
                u64 v = __hip_atomic_load(hb64 + (size_t)(tbase + r) * 128 + kw,
                                          __ATOMIC_RELAXED, __HIP_MEMORY_SCOPE_AGENT);
                lh64[r * 128 + (kw ^ ((r & 7) << 1))] = v;
            }
        }
        __syncthreads();

        f32x4 acc = {0.f, 0.f, 0.f, 0.f};
#pragma unroll
        for (int kk = 0; kk < 16; ++kk) {
            int kb = kk * 32 + fo * 8;
            bf16x8 b = *(bf16x8*)&lh[fr * 512 + (kb ^ ((fr & 7) << 3))];
            acc = __builtin_amdgcn_mfma_f32_16x16x32_bf16(a[kk], b, acc, 0, 0, 0);
        }
        *(f32x4*)&ghs[gate][fr][cpos * 16 + fo * 4] = acc;
        __syncthreads();

        if (ep) {
            float r0 = sigmoidf_(gis[0][et][ec]     + ghs[0][et][ec]     + bs_r0);
            float r1 = sigmoidf_(gis[0][et][ec + 1] + ghs[0][et][ec + 1] + bs_r1);
            float z0 = sigmoidf_(gis[1][et][ec]     + ghs[1][et][ec]     + bs_z0);
            float z1 = sigmoidf_(gis[1][et][ec + 1] + ghs[1][et][ec + 1] + bs_z1);
            float n0 = tanhf_(gis[2][et][ec]     + bi_n0 + r0 * (ghs[2][et][ec]     + bh_n0));
            float n1 = tanhf_(gis[2][et][ec + 1] + bi_n1 + r1 * (ghs[2][et][ec + 1] + bh_n1));
            hreg0 = (1.f - z0) * n0 + z0 * hreg0;
            hreg1 = (1.f - z1) * n1 + z1 * hreg1;
            unsigned packv = (unsigned)f2bf(hreg0) | ((unsigned)f2bf(hreg1) << 16);
            __hip_atomic_store(
                (unsigned*)out_bf + ((((size_t)step * 512 + tbase + et) * 512 + cbase + ec) >> 1),
                packv, __ATOMIC_RELAXED, __HIP_MEMORY_SCOPE_AGENT);
        }
        __syncthreads();   // drains h stores; also fences gis reads before rewrite

        if (step < 63) {
            if (tid == 0)
                __hip_atomic_store(&flags[(tg * 8 + cb) * 32], (unsigned)(step + 1),
                                   __ATOMIC_RELAXED, __HIP_MEMORY_SCOPE_AGENT);
            gi_compute(step + 1);   // hidden under the peer-flag poll
            if (tid < 8) {
                unsigned tgt = (unsigned)(step + 1);
                while (__hip_atomic_load(&flags[(tg * 8 + tid) * 32],
                                         __ATOMIC_RELAXED, __HIP_MEMORY_SCOPE_AGENT) < tgt)
                    __builtin_amdgcn_s_sleep(1);
            }
            __syncthreads();
        }
    }
}

// ---------------------------------------------------------------------------
extern "C" void kernel_launch(void* const* d_in, const int* in_sizes, int n_in,
                              void* d_out, int out_size, void* d_ws, size_t ws_size,
                              hipStream_t stream)
{
    const float* state   = (const float*)d_in[0];
    const float* action  = (const float*)d_in[1];
    const float* ae_w1   = (const float*)d_in[2];
    const float* ae_b1   = (const float*)d_in[3];
    const float* ae_w2   = (const float*)d_in[4];
    const float* ae_b2   = (const float*)d_in[5];
    const float* ln2_g   = (const float*)d_in[8];
    const float* ln2_b   = (const float*)d_in[9];
    const float* wv      = (const float*)d_in[14];
    const float* bv      = (const float*)d_in[15];
    const float* wo      = (const float*)d_in[16];
    const float* bo      = (const float*)d_in[17];
    const float* gru_wih = (const float*)d_in[18];
    const float* gru_bih = (const float*)d_in[19];
    const float* gru_whh = (const float*)d_in[20];
    const float* gru_bhh = (const float*)d_in[21];
    const float* mlp_w   = (const float*)d_in[22];
    const float* mlp_b   = (const float*)d_in[23];

    char* ws = (char*)d_ws;
    size_t off = 0;
    auto carve = [&](size_t bytes) -> char* {
        char* p = ws + off; off = (off + bytes + 255) & ~(size_t)255; return p;
    };
    u16*   kv_bf  = (u16*)carve(32768ull * 256 * 2);
    u16*   x_bf   = (u16*)carve(32768ull * 256 * 2);
    u16*   out_bf = (u16*)carve(32768ull * 512 * 2);
    u16*   WfT    = (u16*)carve(256 * 256 * 2);
    float* bfv    = (float*)carve(256 * 4);
    u16*   wihT   = (u16*)carve(1536 * 256 * 2);
    u16*   whhT   = (u16*)carve(1536 * 512 * 2);
    u16*   mlpT   = (u16*)carve(256 * 512 * 2);
    u16*   w2T    = (u16*)carve(256 * 128 * 2);
    u16*   h0_bf  = (u16*)carve(512 * 512 * 2);
    unsigned* flags = (unsigned*)carve(32 * 8 * 32 * 4);

    // single prep launch: transposes, WfT, fused bias, zero-fills
    prep_all<<<714, 256, 0, stream>>>(wv, wo, gru_wih, gru_whh, mlp_w, ae_w2,
                                      bv, bo, WfT, wihT, whhT, mlpT, w2T,
                                      bfv, h0_bf, flags);

    ae_ln_mfma<<<512, 256, 0, stream>>>(action, ae_w1, ae_b1, w2T, ae_b2,
                                        ln2_g, ln2_b, kv_bf);

    // x = state + kv_in @ Wf + bfv   (bf16 out)
    gemm128<0><<<dim3(256, 2), 256, 0, stream>>>(kv_bf, WfT, bfv, state, x_bf, nullptr, 256, 256);

    // GRU (gi computed in-kernel): one persistent cooperative kernel
    {
        void* args[] = { (void*)&whhT, (void*)&wihT, (void*)&gru_bhh, (void*)&gru_bih,
                         (void*)&x_bf, (void*)&h0_bf, (void*)&out_bf, (void*)&flags };
        hipError_t cerr = hipLaunchCooperativeKernel((const void*)gru_persistent11,
                                                     dim3(256), dim3(768), args, 0, stream);
        if (cerr != hipSuccess) {
            gru_persistent11<<<dim3(256), dim3(768), 0, stream>>>(
                whhT, wihT, gru_bhh, gru_bih, x_bf, h0_bf, out_bf, flags);
        }
    }

    // states = out @ mlp_w + mlp_b   (f32 out + last-row duplicate)
    gemm128<2><<<dim3(256, 2), 256, 0, stream>>>(out_bf, mlpT, mlp_b, nullptr, nullptr,
                                                 (float*)d_out, 256, 512);
}

// Round 18
// 356.743 us; speedup vs baseline: 1.6999x; 1.6999x over previous
//
#include <hip/hip_runtime.h>
#include <hip/hip_bf16.h>

typedef unsigned short u16;
typedef unsigned long long u64;
typedef __attribute__((ext_vector_type(8))) short bf16x8;
typedef __attribute__((ext_vector_type(4))) float f32x4;

static __device__ __forceinline__ u16 f2bf(float f) {
    union { float f; unsigned u; } cv; cv.f = f;
    unsigned u = cv.u;
    unsigned r = u + 0x7FFF + ((u >> 16) & 1);   // round-to-nearest-even
    return (u16)(r >> 16);
}
static __device__ __forceinline__ float bf2f(u16 b) {
    union { unsigned u; float f; } cv; cv.u = ((unsigned)b) << 16;
    return cv.f;
}
static __device__ __forceinline__ float sigmoidf_(float x) {
    return 1.0f / (1.0f + __expf(-x));
}
static __device__ __forceinline__ float tanhf_(float x) {
    float e = __expf(-2.f * fabsf(x));
    float t = (1.f - e) / (1.f + e);
    return copysignf(t, x);
}

// ---------------------------------------------------------------------------
// One-launch preprocessing. Job map (714 blocks):
//   0..95    wihT tiles       96..287  whhT tiles     288..319 mlpT tiles
//   320..327 w2T tiles        328      bfv            329..456 h0 zero
//   457      flags zero       458..713 WfT direct (wv@wo)^T
__global__ __launch_bounds__(256) void prep_all(
    const float* __restrict__ wv, const float* __restrict__ wo,
    const float* __restrict__ wih, const float* __restrict__ whh,
    const float* __restrict__ mlp, const float* __restrict__ w2,
    const float* __restrict__ bv, const float* __restrict__ bo,
    u16* __restrict__ WfT, u16* __restrict__ wihT,
    u16* __restrict__ whhT, u16* __restrict__ mlpT, u16* __restrict__ w2T,
    float* __restrict__ bfv, u16* __restrict__ h0_bf,
    unsigned* __restrict__ flags)
{
    __shared__ u16 t[64][66];
    int bid = blockIdx.x, tid = threadIdx.x;

    if (bid >= 458) {                     // WfT[j][i] = bf16(sum_k wv[i][k]*wo[k][j])
        int j = bid - 458, i = tid;
        float s = 0.f;
        for (int k = 0; k < 256; ++k) s = fmaf(wv[i * 256 + k], wo[k * 256 + j], s);
        WfT[j * 256 + i] = f2bf(s);
        return;
    }
    if (bid == 328) {                     // bfv = bo + bv@wo
        int j = tid;
        float s = bo[j];
        for (int k = 0; k < 256; ++k) s = fmaf(bv[k], wo[k * 256 + j], s);
        bfv[j] = s;
        return;
    }
    if (bid >= 329 && bid < 457) {        // zero h0_bf (512KB)
        int i = ((bid - 329) * 256 + tid) * 2;
        u64* p = (u64*)h0_bf;
        p[i] = 0; p[i + 1] = 0;
        return;
    }
    if (bid == 457) {                     // zero flags
        unsigned* p = flags;
        for (int i = tid; i < 32 * 8 * 32; i += 256) p[i] = 0u;
        return;
    }

    // tiled transpose-convert jobs: dst[n*K+k] = bf16(src[k*N+n])
    const float* src; u16* dst; int K, N, bx, by;
    if (bid < 96)       { src = wih; dst = wihT; K = 256; N = 1536; int l = bid;       bx = l & 3; by = l >> 2; }
    else if (bid < 288) { src = whh; dst = whhT; K = 512; N = 1536; int l = bid - 96;  bx = l & 7; by = l >> 3; }
    else if (bid < 320) { src = mlp; dst = mlpT; K = 512; N = 256;  int l = bid - 288; bx = l & 7; by = l >> 3; }
    else                { src = w2;  dst = w2T;  K = 128; N = 256;  int l = bid - 320; bx = l & 1; by = l >> 1; }

    int k0 = bx * 64, n0 = by * 64;
    int r = tid >> 4, c4 = (tid & 15) * 4;
#pragma unroll
    for (int p = 0; p < 4; ++p) {
        int row = r + p * 16;
        float4 v = *(const float4*)&src[(size_t)(k0 + row) * N + n0 + c4];
        t[c4 + 0][row] = f2bf(v.x);
        t[c4 + 1][row] = f2bf(v.y);
        t[c4 + 2][row] = f2bf(v.z);
        t[c4 + 3][row] = f2bf(v.w);
    }
    __syncthreads();
    int rr = tid >> 3, cc = (tid & 7) * 8;
#pragma unroll
    for (int p = 0; p < 2; ++p) {
        int row = rr + p * 32;
        u16 pack[8];
#pragma unroll
        for (int j = 0; j < 8; ++j) pack[j] = t[row][cc + j];
        *(uint4*)&dst[(size_t)(n0 + row) * K + k0 + cc] = *(uint4*)pack;
    }
}

// ---------------------------------------------------------------------------
// Fused action-encoder + LayerNorm, MFMA version. 64 positions per block.
__global__ __launch_bounds__(256) void ae_ln_mfma(
    const float* __restrict__ action,
    const float* __restrict__ w1, const float* __restrict__ b1,
    const u16* __restrict__ w2T, const float* __restrict__ b2,
    const float* __restrict__ g, const float* __restrict__ be,
    u16* __restrict__ kvbf)
{
    __shared__ u16 lB[256][136];
    __shared__ u16 lA[64][136];
    int tid = threadIdx.x;
    long base = (long)blockIdx.x * 64;

    for (int idx = tid; idx < 256 * 16; idx += 256) {
        int r = idx >> 4, ch = (idx & 15) * 8;
        *(uint4*)&lB[r][ch] = *(const uint4*)&w2T[r * 128 + ch];
    }
    for (int idx = tid; idx < 8192; idx += 256) {
        int r = idx >> 7, k = idx & 127;
        float a0 = action[(base + r) * 2], a1 = action[(base + r) * 2 + 1];
        float v = fmaf(a1, w1[128 + k], fmaf(a0, w1[k], b1[k]));
        lA[r][k] = f2bf(v > 0.f ? v : 0.f);
    }
    __syncthreads();

    int wv = tid >> 6, l = tid & 63;
    int fr = l & 15, fq = l >> 4;
    f32x4 acc[4][4] = {};
#pragma unroll
    for (int ks = 0; ks < 4; ++ks) {
        bf16x8 a[4], b[4];
#pragma unroll
        for (int mi = 0; mi < 4; ++mi) a[mi] = *(bf16x8*)&lA[mi * 16 + fr][ks * 32 + fq * 8];
#pragma unroll
        for (int ni = 0; ni < 4; ++ni) b[ni] = *(bf16x8*)&lB[wv * 64 + ni * 16 + fr][ks * 32 + fq * 8];
#pragma unroll
        for (int mi = 0; mi < 4; ++mi)
#pragma unroll
            for (int ni = 0; ni < 4; ++ni)
                acc[mi][ni] = __builtin_amdgcn_mfma_f32_16x16x32_bf16(a[mi], b[ni], acc[mi][ni], 0, 0, 0);
    }
    __syncthreads();

    float* e = (float*)&lB[0][0];
#pragma unroll
    for (int mi = 0; mi < 4; ++mi)
#pragma unroll
        for (int ni = 0; ni < 4; ++ni) {
            int col = wv * 64 + ni * 16 + fr;
            float bb = b2[col];
#pragma unroll
            for (int reg = 0; reg < 4; ++reg)
                e[(mi * 16 + fq * 4 + reg) * 261 + col] = acc[mi][ni][reg] + bb;
        }
    __syncthreads();

    int t = tid >> 2, sub = tid & 3;
    float s = 0.f, ss = 0.f;
#pragma unroll
    for (int i = 0; i < 64; ++i) {
        float v = e[t * 261 + sub + i * 4];
        s += v; ss += v * v;
    }
    s += __shfl_xor(s, 1); ss += __shfl_xor(ss, 1);
    s += __shfl_xor(s, 2); ss += __shfl_xor(ss, 2);
    float m = s * (1.f / 256.f);
    float var = ss * (1.f / 256.f) - m * m;
    float rs = rsqrtf(var + 1e-5f);
#pragma unroll
    for (int i8 = 0; i8 < 8; ++i8) {
        u16 pack[8];
#pragma unroll
        for (int j = 0; j < 8; ++j) {
            int col = sub * 64 + i8 * 8 + j;
            float v = (e[t * 261 + col] - m) * rs * g[col] + be[col];
            pack[j] = f2bf(v);
        }
        *(uint4*)&kvbf[(base + t) * 256 + sub * 64 + i8 * 8] = *(uint4*)pack;
    }
}

// ---------------------------------------------------------------------------
// 128x128-tile bf16 GEMM, BK=64: C = A[M,K] @ BT[N,K]^T (+bias[col]) (+modes)
template <int MODE>
__global__ __launch_bounds__(256) void gemm128(
    const u16* __restrict__ A, const u16* __restrict__ BT,
    const float* __restrict__ bias, const float* __restrict__ resid,
    u16* __restrict__ outBf, float* __restrict__ outF,
    int N, int K)
{
    __shared__ u16 lA[128][72];
    __shared__ u16 lB[128][72];
    int tid = threadIdx.x;
    int bm = blockIdx.x * 128, bn = blockIdx.y * 128;

    f32x4 acc[4][4] = {};
    int w = tid >> 6, l = tid & 63;
    int wr = (w >> 1) * 64, wc = (w & 1) * 64;
    int fr = l & 15, fk = (l >> 4) * 8;

    for (int k0 = 0; k0 < K; k0 += 64) {
#pragma unroll
        for (int i = 0; i < 4; ++i) {
            int idx = tid + i * 256;
            int r = idx >> 3, c8 = (idx & 7) * 8;
            *(uint4*)&lA[r][c8] = *(const uint4*)&A[(long)(bm + r) * K + k0 + c8];
            *(uint4*)&lB[r][c8] = *(const uint4*)&BT[(long)(bn + r) * K + k0 + c8];
        }
        __syncthreads();
#pragma unroll
        for (int half = 0; half < 2; ++half) {
            int fo = half * 32 + fk;
            bf16x8 a[4], b[4];
#pragma unroll
            for (int mi = 0; mi < 4; ++mi) a[mi] = *(bf16x8*)&lA[wr + mi * 16 + fr][fo];
#pragma unroll
            for (int ni = 0; ni < 4; ++ni) b[ni] = *(bf16x8*)&lB[wc + ni * 16 + fr][fo];
#pragma unroll
            for (int mi = 0; mi < 4; ++mi)
#pragma unroll
                for (int ni = 0; ni < 4; ++ni)
                    acc[mi][ni] = __builtin_amdgcn_mfma_f32_16x16x32_bf16(a[mi], b[ni], acc[mi][ni], 0, 0, 0);
        }
        __syncthreads();
    }

#pragma unroll
    for (int mi = 0; mi < 4; ++mi)
#pragma unroll
        for (int ni = 0; ni < 4; ++ni) {
            int c = bn + wc + ni * 16 + fr;
            float bz = bias[c];
#pragma unroll
            for (int reg = 0; reg < 4; ++reg) {
                int r = bm + wr + mi * 16 + (l >> 4) * 4 + reg;
                float v = acc[mi][ni][reg] + bz;
                if constexpr (MODE == 0) {
                    v += resid[(long)r * N + c];
                    outBf[(long)r * N + c] = f2bf(v);
                } else if constexpr (MODE == 1) {
                    outBf[(long)r * N + c] = f2bf(v);
                } else {
                    outF[(long)r * N + c] = v;
                    if ((r & 511) == 511) outF[8388608 + (long)(r >> 9) * N + c] = v;
                }
            }
        }
}

// ---------------------------------------------------------------------------
// Persistent GRU v6 (known-good, 218us) + fast tanh. 256 blocks = 32 t-groups
// x 8 col-blocks (64 cols each), 768 threads = 12 waves = (cpos 0..3, gate 0..2).
// Proven local optimum: 6 structural variants (antiphase, gi-fuse x2, mlp-fuse,
// fan-4) all regressed. Per-step ~3.4us = ~1us compute + ~2.4us cross-XCD
// h-broadcast round trip (store->L3->flag->poll->load).
__global__ __launch_bounds__(768, 1) void gru_persistent6(
    const u16* __restrict__ whhT, const float* __restrict__ bhh,
    const u16* __restrict__ gi_bf, const u16* __restrict__ h0_bf,
    u16* __restrict__ out_bf, unsigned* __restrict__ flags)
{
    __shared__ u64 lh64[2048];                       // swizzled h [16][512] bf16
    __shared__ __align__(16) float ghs[3][16][68];   // [gate][t_loc][c_loc]
    u16* lh = (u16*)lh64;

    int tid = threadIdx.x;
    int bid = blockIdx.x;
    int tg = bid >> 3, cb = bid & 7;
    int tbase = tg * 16, cbase = cb * 64;

    int w = tid >> 6, l = tid & 63;
    int fr = l & 15, fo = l >> 4;
    int cpos = w & 3, gate = w >> 2;

    bf16x8 a[16];
    {
        const u16* wp = whhT + ((size_t)(gate << 9) + cbase + cpos * 16 + fr) * 512 + fo * 8;
#pragma unroll
        for (int kk = 0; kk < 16; ++kk)
            a[kk] = *(const bf16x8*)(wp + kk * 32);
    }

    int et = tid >> 5, ec = (tid & 31) * 2;
    bool ep = tid < 512;
    float hreg0 = 0.f, hreg1 = 0.f;
    float bh_r0 = 0, bh_r1 = 0, bh_z0 = 0, bh_z1 = 0, bh_n0 = 0, bh_n1 = 0;
    if (ep) {
        bh_r0 = bhh[cbase + ec];        bh_r1 = bhh[cbase + ec + 1];
        bh_z0 = bhh[512 + cbase + ec];  bh_z1 = bhh[512 + cbase + ec + 1];
        bh_n0 = bhh[1024 + cbase + ec]; bh_n1 = bhh[1024 + cbase + ec + 1];
    }

    const unsigned* gp = (const unsigned*)gi_bf;
    unsigned g_r = 0, g_z = 0, g_n = 0;
    if (ep) {
        size_t grow = (size_t)(tbase + et) * 1536;
        g_r = gp[(grow + cbase + ec) >> 1];
        g_z = gp[(grow + 512 + cbase + ec) >> 1];
        g_n = gp[(grow + 1024 + cbase + ec) >> 1];
    }

    for (int step = 0; step < 64; ++step) {
        const u64* hb64 = (const u64*)(step ? out_bf + (size_t)(step - 1) * 262144
                                           : h0_bf);
#pragma unroll
        for (int i = 0; i < 3; ++i) {
            int idx = tid + i * 768;
            if (idx < 2048) {
                int r = idx >> 7, kw = idx & 127;
                u64 v = __hip_atomic_load(hb64 + (size_t)(tbase + r) * 128 + kw,
                                          __ATOMIC_RELAXED, __HIP_MEMORY_SCOPE_AGENT);
                lh64[r * 128 + (kw ^ ((r & 7) << 1))] = v;
            }
        }
        __syncthreads();

        f32x4 acc = {0.f, 0.f, 0.f, 0.f};
#pragma unroll
        for (int kk = 0; kk < 16; ++kk) {
            int kb = kk * 32 + fo * 8;
            bf16x8 b = *(bf16x8*)&lh[fr * 512 + (kb ^ ((fr & 7) << 3))];
            acc = __builtin_amdgcn_mfma_f32_16x16x32_bf16(a[kk], b, acc, 0, 0, 0);
        }
        *(f32x4*)&ghs[gate][fr][cpos * 16 + fo * 4] = acc;
        __syncthreads();

        if (ep) {
            float ghr0 = ghs[0][et][ec], ghr1 = ghs[0][et][ec + 1];
            float ghz0 = ghs[1][et][ec], ghz1 = ghs[1][et][ec + 1];
            float ghn0 = ghs[2][et][ec], ghn1 = ghs[2][et][ec + 1];
            float r0 = sigmoidf_(bf2f((u16)(g_r & 0xffff)) + ghr0 + bh_r0);
            float r1 = sigmoidf_(bf2f((u16)(g_r >> 16)) + ghr1 + bh_r1);
            float z0 = sigmoidf_(bf2f((u16)(g_z & 0xffff)) + ghz0 + bh_z0);
            float z1 = sigmoidf_(bf2f((u16)(g_z >> 16)) + ghz1 + bh_z1);
            float n0 = tanhf_(bf2f((u16)(g_n & 0xffff)) + r0 * (ghn0 + bh_n0));
            float n1 = tanhf_(bf2f((u16)(g_n >> 16)) + r1 * (ghn1 + bh_n1));
            hreg0 = (1.f - z0) * n0 + z0 * hreg0;
            hreg1 = (1.f - z1) * n1 + z1 * hreg1;
            unsigned packv = (unsigned)f2bf(hreg0) | ((unsigned)f2bf(hreg1) << 16);
            __hip_atomic_store(
                (unsigned*)out_bf + ((((size_t)step * 512 + tbase + et) * 512 + cbase + ec) >> 1),
                packv, __ATOMIC_RELAXED, __HIP_MEMORY_SCOPE_AGENT);
        }
        __syncthreads();

        if (step < 63) {
            if (tid == 0)
                __hip_atomic_store(&flags[(tg * 8 + cb) * 32], (unsigned)(step + 1),
                                   __ATOMIC_RELAXED, __HIP_MEMORY_SCOPE_AGENT);
            if (ep) {
                size_t grow = ((size_t)(step + 1) * 512 + tbase + et) * 1536;
                g_r = gp[(grow + cbase + ec) >> 1];
                g_z = gp[(grow + 512 + cbase + ec) >> 1];
                g_n = gp[(grow + 1024 + cbase + ec) >> 1];
            }
            if (tid < 8) {
                unsigned tgt = (unsigned)(step + 1);
                while (__hip_atomic_load(&flags[(tg * 8 + tid) * 32],
                                         __ATOMIC_RELAXED, __HIP_MEMORY_SCOPE_AGENT) < tgt)
                    __builtin_amdgcn_s_sleep(1);
            }
            __syncthreads();
        }
    }
}

// ---------------------------------------------------------------------------
extern "C" void kernel_launch(void* const* d_in, const int* in_sizes, int n_in,
                              void* d_out, int out_size, void* d_ws, size_t ws_size,
                              hipStream_t stream)
{
    const float* state   = (const float*)d_in[0];
    const float* action  = (const float*)d_in[1];
    const float* ae_w1   = (const float*)d_in[2];
    const float* ae_b1   = (const float*)d_in[3];
    const float* ae_w2   = (const float*)d_in[4];
    const float* ae_b2   = (const float*)d_in[5];
    const float* ln2_g   = (const float*)d_in[8];
    const float* ln2_b   = (const float*)d_in[9];
    const float* wv      = (const float*)d_in[14];
    const float* bv      = (const float*)d_in[15];
    const float* wo      = (const float*)d_in[16];
    const float* bo      = (const float*)d_in[17];
    const float* gru_wih = (const float*)d_in[18];
    const float* gru_bih = (const float*)d_in[19];
    const float* gru_whh = (const float*)d_in[20];
    const float* gru_bhh = (const float*)d_in[21];
    const float* mlp_w   = (const float*)d_in[22];
    const float* mlp_b   = (const float*)d_in[23];

    char* ws = (char*)d_ws;
    size_t off = 0;
    auto carve = [&](size_t bytes) -> char* {
        char* p = ws + off; off = (off + bytes + 255) & ~(size_t)255; return p;
    };
    u16*   kv_bf  = (u16*)carve(32768ull * 256 * 2);
    u16*   x_bf   = (u16*)carve(32768ull * 256 * 2);
    u16*   gi_bf  = (u16*)carve(32768ull * 1536 * 2);
    u16*   out_bf = (u16*)carve(32768ull * 512 * 2);
    u16*   WfT    = (u16*)carve(256 * 256 * 2);
    float* bfv    = (float*)carve(256 * 4);
    u16*   wihT   = (u16*)carve(1536 * 256 * 2);
    u16*   whhT   = (u16*)carve(1536 * 512 * 2);
    u16*   mlpT   = (u16*)carve(256 * 512 * 2);
    u16*   w2T    = (u16*)carve(256 * 128 * 2);
    u16*   h0_bf  = (u16*)carve(512 * 512 * 2);
    unsigned* flags = (unsigned*)carve(32 * 8 * 32 * 4);

    // single prep launch: transposes, WfT, fused bias, zero-fills
    prep_all<<<714, 256, 0, stream>>>(wv, wo, gru_wih, gru_whh, mlp_w, ae_w2,
                                      bv, bo, WfT, wihT, whhT, mlpT, w2T,
                                      bfv, h0_bf, flags);

    ae_ln_mfma<<<512, 256, 0, stream>>>(action, ae_w1, ae_b1, w2T, ae_b2,
                                        ln2_g, ln2_b, kv_bf);

    // x = state + kv_in @ Wf + bfv   (bf16 out)
    gemm128<0><<<dim3(256, 2), 256, 0, stream>>>(kv_bf, WfT, bfv, state, x_bf, nullptr, 256, 256);
    // gi = x @ wih + bih             (bf16 out)
    gemm128<1><<<dim3(256, 12), 256, 0, stream>>>(x_bf, wihT, gru_bih, nullptr, gi_bf, nullptr, 1536, 256);

    // GRU: one persistent cooperative kernel, all 64 steps
    {
        void* args[] = { (void*)&whhT, (void*)&gru_bhh, (void*)&gi_bf,
                         (void*)&h0_bf, (void*)&out_bf, (void*)&flags };
        hipError_t cerr = hipLaunchCooperativeKernel((const void*)gru_persistent6,
                                                     dim3(256), dim3(768), args, 0, stream);
        if (cerr != hipSuccess) {
            gru_persistent6<<<dim3(256), dim3(768), 0, stream>>>(
                whhT, gru_bhh, gi_bf, h0_bf, out_bf, flags);
        }
    }

    // states = out @ mlp_w + mlp_b   (f32 out + last-row duplicate)
    gemm128<2><<<dim3(256, 2), 256, 0, stream>>>(out_bf, mlpT, mlp_b, nullptr, nullptr,
                                                 (float*)d_out, 256, 512);
}